// Round 9
// baseline (584.558 us; speedup 1.0000x reference)
//
#include <hip/hip_runtime.h>
#include <hip/hip_bf16.h>
#include <hip/hip_cooperative_groups.h>

// Round 9: cooperative mega-kernel, fixed launch config (512 blocks,
// launch_bounds(256,2): VGPR cap 256 >= ~196 unified demand, LDS 2x48K/CU)
// + CHECKED return code with full separate-kernel fallback (r6 qkv + r7 attn).
// P0 cvt x + transpose W; P1 qkv queue(768); P2 attn 128-row queue(512,
// heavy-first); P3 out static 1:1.

namespace cg = cooperative_groups;

typedef __bf16 bf16_t;
typedef __bf16 bf16x4 __attribute__((ext_vector_type(4)));
typedef __bf16 bf16x8 __attribute__((ext_vector_type(8)));
typedef float f32x4 __attribute__((ext_vector_type(4)));

__device__ int g_j1, g_j2;

__device__ __forceinline__ void barrier_lgkm() {
    asm volatile("s_waitcnt lgkmcnt(0)\n\ts_barrier" ::: "memory");
}

__device__ __forceinline__ float exp_pwrite(f32x4 sc[4], bf16_t* Ps,
                                            int wave, int quad, int l16) {
    float part = 0.f;
    int rowbase = (wave * 16 + l16) * 64;
    int gran = (quad & 1) * 4;
    int chi = quad >> 1;
#pragma unroll
    for (int nt = 0; nt < 4; nt++) {
        f32x4 p;
#pragma unroll
        for (int rr = 0; rr < 4; rr++) {
            p[rr] = __builtin_amdgcn_exp2f(sc[nt][rr]);
            part += p[rr];
        }
        bf16x4 pb;
#pragma unroll
        for (int rr = 0; rr < 4; rr++) pb[rr] = (bf16_t)p[rr];
        int cc = (nt * 2 + chi) ^ (l16 & 7);
        *(bf16x4*)(Ps + rowbase + cc * 8 + gran) = pb;
    }
    part += __shfl_xor(part, 16);
    part += __shfl_xor(part, 32);
    return part;
}

// ---------- shared device bodies (used by mega phases AND fallback kernels) ----------

// qkv GEMM body: bf16 A (xb), 128x128 tile job (mb,nb,z)
__device__ __forceinline__ void qkv_body(
    int mb, int nb, int z, const bf16_t* xb, const bf16_t* WqT,
    const bf16_t* WkT, const bf16_t* WvT, bf16_t* Qb, bf16_t* Kb, bf16_t* Vb,
    bf16_t* As, bf16_t* Bs, int tid, int wave, int quad, int l16) {
    const int KD = 1024;
    const bf16_t* BT = (z == 0) ? WqT : (z == 1) ? WkT : WvT;
    int m0 = mb * 128, n0 = nb * 128;
    int wm = wave >> 1, wn = wave & 1;
    int r = tid >> 2;
    int c8 = (((tid & 3) ^ ((tid >> 3) & 3))) * 8;
    const bf16_t* gA0 = xb + (size_t)(m0 + r) * KD + c8;
    const bf16_t* gA1 = xb + (size_t)(m0 + 64 + r) * KD + c8;
    const bf16_t* gB0 = BT + (size_t)(n0 + r) * KD + c8;
    const bf16_t* gB1 = BT + (size_t)(n0 + 64 + r) * KD + c8;

    f32x4 acc[4][4];
#pragma unroll
    for (int i = 0; i < 4; i++)
#pragma unroll
        for (int j = 0; j < 4; j++) acc[i][j] = (f32x4){0.f, 0.f, 0.f, 0.f};

    int4 sa0 = *(const int4*)gA0, sa1 = *(const int4*)gA1;
    int4 sb0 = *(const int4*)gB0, sb1 = *(const int4*)gB1;
    *(int4*)(As + tid * 8) = sa0;
    *(int4*)(As + 2048 + tid * 8) = sa1;
    *(int4*)(Bs + tid * 8) = sb0;
    *(int4*)(Bs + 2048 + tid * 8) = sb1;
    sa0 = *(const int4*)(gA0 + 32); sa1 = *(const int4*)(gA1 + 32);
    sb0 = *(const int4*)(gB0 + 32); sb1 = *(const int4*)(gB1 + 32);

    int csw = (quad ^ ((l16 >> 1) & 3)) * 8;
#pragma unroll 1
    for (int kk = 0; kk < 32; kk += 2) {
        barrier_lgkm();
        bf16x8 af[4], bfr[4];
#pragma unroll
        for (int mt = 0; mt < 4; mt++)
            af[mt] = *(const bf16x8*)(As + (wm * 64 + mt * 16 + l16) * 32 + csw);
#pragma unroll
        for (int nt = 0; nt < 4; nt++)
            bfr[nt] = *(const bf16x8*)(Bs + (wn * 64 + nt * 16 + l16) * 32 + csw);
        *(int4*)(As + 4096 + tid * 8) = sa0;
        *(int4*)(As + 6144 + tid * 8) = sa1;
        *(int4*)(Bs + 4096 + tid * 8) = sb0;
        *(int4*)(Bs + 6144 + tid * 8) = sb1;
        if (kk + 2 < 32) {
            int k0 = (kk + 2) * 32;
            sa0 = *(const int4*)(gA0 + k0); sa1 = *(const int4*)(gA1 + k0);
            sb0 = *(const int4*)(gB0 + k0); sb1 = *(const int4*)(gB1 + k0);
        }
        if (z == 2) {
#pragma unroll
            for (int mt = 0; mt < 4; mt++)
#pragma unroll
                for (int nt = 0; nt < 4; nt++)
                    acc[mt][nt] = __builtin_amdgcn_mfma_f32_16x16x32_bf16(
                        bfr[nt], af[mt], acc[mt][nt], 0, 0, 0);
        } else {
#pragma unroll
            for (int mt = 0; mt < 4; mt++)
#pragma unroll
                for (int nt = 0; nt < 4; nt++)
                    acc[mt][nt] = __builtin_amdgcn_mfma_f32_16x16x32_bf16(
                        af[mt], bfr[nt], acc[mt][nt], 0, 0, 0);
        }
        barrier_lgkm();
#pragma unroll
        for (int mt = 0; mt < 4; mt++)
            af[mt] = *(const bf16x8*)(As + 4096 + (wm * 64 + mt * 16 + l16) * 32 + csw);
#pragma unroll
        for (int nt = 0; nt < 4; nt++)
            bfr[nt] = *(const bf16x8*)(Bs + 4096 + (wn * 64 + nt * 16 + l16) * 32 + csw);
        if (kk + 2 < 32) {
            *(int4*)(As + tid * 8) = sa0;
            *(int4*)(As + 2048 + tid * 8) = sa1;
            *(int4*)(Bs + tid * 8) = sb0;
            *(int4*)(Bs + 2048 + tid * 8) = sb1;
            if (kk + 3 < 32) {
                int k0 = (kk + 3) * 32;
                sa0 = *(const int4*)(gA0 + k0); sa1 = *(const int4*)(gA1 + k0);
                sb0 = *(const int4*)(gB0 + k0); sb1 = *(const int4*)(gB1 + k0);
            }
        }
        if (z == 2) {
#pragma unroll
            for (int mt = 0; mt < 4; mt++)
#pragma unroll
                for (int nt = 0; nt < 4; nt++)
                    acc[mt][nt] = __builtin_amdgcn_mfma_f32_16x16x32_bf16(
                        bfr[nt], af[mt], acc[mt][nt], 0, 0, 0);
        } else {
#pragma unroll
            for (int mt = 0; mt < 4; mt++)
#pragma unroll
                for (int nt = 0; nt < 4; nt++)
                    acc[mt][nt] = __builtin_amdgcn_mfma_f32_16x16x32_bf16(
                        af[mt], bfr[nt], acc[mt][nt], 0, 0, 0);
        }
    }

    if (z == 0) {
#pragma unroll
        for (int mt = 0; mt < 4; mt++) {
            int mg_base = m0 + (wave >> 1) * 64 + mt * 16 + quad * 4;
#pragma unroll
            for (int nt = 0; nt < 4; nt++) {
                int ng = n0 + (wave & 1) * 64 + nt * 16 + l16;
                int h = ng >> 6, d = ng & 63;
#pragma unroll
                for (int rr = 0; rr < 4; rr++) {
                    int mg = mg_base + rr;
                    int b = mg >> 11, s = mg & 2047;
                    Qb[(((size_t)(b * 16 + h) * 2048) + s) * 64 + d] =
                        (bf16_t)acc[mt][nt][rr];
                }
            }
        }
    } else if (z == 1) {
#pragma unroll
        for (int mt = 0; mt < 4; mt++) {
            int mg_base = m0 + (wave >> 1) * 64 + mt * 16 + quad * 4;
#pragma unroll
            for (int nt = 0; nt < 4; nt++) {
                int ng = n0 + (wave & 1) * 64 + nt * 16 + l16;
                int h = ng >> 6, dd = ng & 63;
#pragma unroll
                for (int rr = 0; rr < 4; rr++) {
                    int mg = mg_base + rr;
                    int b = mg >> 11, sl = mg & 2047;
                    int kt = sl >> 6, row = sl & 63;
                    int cc = (dd >> 3) ^ (row & 7);
                    Kb[(size_t)(b * 16 + h) * 131072 + kt * 4096 + row * 64 +
                       cc * 8 + (dd & 7)] = (bf16_t)acc[mt][nt][rr];
                }
            }
        }
    } else {
#pragma unroll
        for (int mt = 0; mt < 4; mt++) {
            int sg = m0 + (wave >> 1) * 64 + mt * 16 + l16;
            int b = sg >> 11, sl = sg & 2047;
            int kt = sl >> 6, srow = sl & 63;
#pragma unroll
            for (int nt = 0; nt < 4; nt++) {
                int dg_base = n0 + (wave & 1) * 64 + nt * 16 + quad * 4;
#pragma unroll
                for (int rr = 0; rr < 4; rr++) {
                    int dg = dg_base + rr;
                    int h = dg >> 6, dd = dg & 63;
                    int cc = (srow >> 3) ^ (dd & 7);
                    Vb[(size_t)(b * 16 + h) * 131072 + kt * 4096 + dd * 64 +
                       cc * 8 + (srow & 7)] = (bf16_t)acc[mt][nt][rr];
                }
            }
        }
    }
}

// attn body: 128 q-rows (qtj), head bh; smem: Ks,Vs(2x4096 each), Ps(2x4096)
__device__ __forceinline__ void attn_body(
    int qtj, int bh, const bf16_t* Qb, const bf16_t* Kb, const bf16_t* Vb,
    bf16_t* ctxb, bf16_t* Ks, bf16_t* Vs, bf16_t* Ps,
    int tid, int wave, int quad, int l16) {
    int h = bh & 15, b = bh >> 4;
    int q0 = qtj * 128;
    const bf16_t* Qbh = Qb + (size_t)bh * 131072;
    const bf16_t* Kbh = Kb + (size_t)bh * 131072;
    const bf16_t* Vbh = Vb + (size_t)bh * 131072;

    const float qs = 0.125f * 1.44269504f;
    bf16x8 aQ[2][2];
#pragma unroll
    for (int sub = 0; sub < 2; sub++) {
        const bf16_t* rq = Qbh + (size_t)(q0 + sub * 64 + wave * 16 + l16) * 64;
#pragma unroll
        for (int ks = 0; ks < 2; ks++) {
            bf16x8 t = *(const bf16x8*)(rq + ks * 32 + quad * 8);
#pragma unroll
            for (int j = 0; j < 8; j++) t[j] = (bf16_t)((float)t[j] * qs);
            aQ[sub][ks] = t;
        }
    }

    float L[2] = {0.f, 0.f};
    f32x4 O[2][4];
#pragma unroll
    for (int sub = 0; sub < 2; sub++)
#pragma unroll
        for (int i = 0; i < 4; i++) O[sub][i] = (f32x4){0.f, 0.f, 0.f, 0.f};

    int tmax = 2 * qtj + 2;
    int4 ska = *(const int4*)(Kbh + tid * 8);
    int4 skb = *(const int4*)(Kbh + 2048 + tid * 8);
    int4 sva = *(const int4*)(Vbh + tid * 8);
    int4 svb = *(const int4*)(Vbh + 2048 + tid * 8);
    *(int4*)(Ks + tid * 8) = ska; *(int4*)(Ks + 2048 + tid * 8) = skb;
    *(int4*)(Vs + tid * 8) = sva; *(int4*)(Vs + 2048 + tid * 8) = svb;
    ska = *(const int4*)(Kbh + 4096 + tid * 8);
    skb = *(const int4*)(Kbh + 6144 + tid * 8);
    sva = *(const int4*)(Vbh + 4096 + tid * 8);
    svb = *(const int4*)(Vbh + 6144 + tid * 8);

#pragma unroll 1
    for (int kt = 0; kt < tmax; kt++) {
        int cur = (kt & 1) * 4096;
        barrier_lgkm();
        bf16x8 kf[4][2], vf[4][2];
#pragma unroll
        for (int nt = 0; nt < 4; nt++) {
            const bf16_t* krow = Ks + cur + (nt * 16 + l16) * 64;
            const bf16_t* vrow = Vs + cur + (nt * 16 + l16) * 64;
#pragma unroll
            for (int ks = 0; ks < 2; ks++) {
                int csw = ((ks * 4 + quad) ^ (l16 & 7)) * 8;
                kf[nt][ks] = *(const bf16x8*)(krow + csw);
                vf[nt][ks] = *(const bf16x8*)(vrow + csw);
            }
        }
        if (kt + 1 < tmax) {
            int nxt = cur ^ 4096;
            *(int4*)(Ks + nxt + tid * 8) = ska;
            *(int4*)(Ks + nxt + 2048 + tid * 8) = skb;
            *(int4*)(Vs + nxt + tid * 8) = sva;
            *(int4*)(Vs + nxt + 2048 + tid * 8) = svb;
        }
        if (kt + 2 < tmax) {
            const bf16_t* kg = Kbh + (kt + 2) * 4096;
            const bf16_t* vg = Vbh + (kt + 2) * 4096;
            ska = *(const int4*)(kg + tid * 8);
            skb = *(const int4*)(kg + 2048 + tid * 8);
            sva = *(const int4*)(vg + tid * 8);
            svb = *(const int4*)(vg + 2048 + tid * 8);
        }

        bool do_lo = (kt < tmax - 1);
        if (do_lo) {
            f32x4 sc[4];
#pragma unroll
            for (int nt = 0; nt < 4; nt++) {
                f32x4 ss = (f32x4){0.f, 0.f, 0.f, 0.f};
                ss = __builtin_amdgcn_mfma_f32_16x16x32_bf16(kf[nt][0], aQ[0][0], ss, 0, 0, 0);
                ss = __builtin_amdgcn_mfma_f32_16x16x32_bf16(kf[nt][1], aQ[0][1], ss, 0, 0, 0);
                sc[nt] = ss;
            }
            if (kt == tmax - 2) {
                int qg = q0 + wave * 16 + l16;
#pragma unroll
                for (int nt = 0; nt < 4; nt++)
#pragma unroll
                    for (int rr = 0; rr < 4; rr++)
                        if (kt * 64 + nt * 16 + quad * 4 + rr > qg) sc[nt][rr] = -1e30f;
            }
            L[0] += exp_pwrite(sc, Ps, wave, quad, l16);
        }
        {
            f32x4 sc[4];
#pragma unroll
            for (int nt = 0; nt < 4; nt++) {
                f32x4 ss = (f32x4){0.f, 0.f, 0.f, 0.f};
                ss = __builtin_amdgcn_mfma_f32_16x16x32_bf16(kf[nt][0], aQ[1][0], ss, 0, 0, 0);
                ss = __builtin_amdgcn_mfma_f32_16x16x32_bf16(kf[nt][1], aQ[1][1], ss, 0, 0, 0);
                sc[nt] = ss;
            }
            if (kt == tmax - 1) {
                int qg = q0 + 64 + wave * 16 + l16;
#pragma unroll
                for (int nt = 0; nt < 4; nt++)
#pragma unroll
                    for (int rr = 0; rr < 4; rr++)
                        if (kt * 64 + nt * 16 + quad * 4 + rr > qg) sc[nt][rr] = -1e30f;
            }
            L[1] += exp_pwrite(sc, Ps + 4096, wave, quad, l16);
        }

#pragma unroll
        for (int ks = 0; ks < 2; ks++) {
            int csw = ((ks * 4 + quad) ^ (l16 & 7)) * 8;
            bf16x8 aPhi = *(const bf16x8*)(Ps + 4096 + (wave * 16 + l16) * 64 + csw);
            bf16x8 aPlo;
            if (do_lo) aPlo = *(const bf16x8*)(Ps + (wave * 16 + l16) * 64 + csw);
#pragma unroll
            for (int nt = 0; nt < 4; nt++) {
                O[1][nt] = __builtin_amdgcn_mfma_f32_16x16x32_bf16(aPhi, vf[nt][ks],
                                                                   O[1][nt], 0, 0, 0);
                if (do_lo)
                    O[0][nt] = __builtin_amdgcn_mfma_f32_16x16x32_bf16(aPlo, vf[nt][ks],
                                                                       O[0][nt], 0, 0, 0);
            }
        }
    }

#pragma unroll
    for (int sub = 0; sub < 2; sub++) {
        float il[4];
#pragma unroll
        for (int rr = 0; rr < 4; rr++) il[rr] = 1.f / __shfl(L[sub], quad * 4 + rr);
#pragma unroll
        for (int nt = 0; nt < 4; nt++) {
#pragma unroll
            for (int rr = 0; rr < 4; rr++) {
                int qoff = q0 + sub * 64 + wave * 16 + quad * 4 + rr;
                int col = h * 64 + nt * 16 + l16;
                ctxb[(size_t)(b * 2048 + qoff) * 1024 + col] =
                    (bf16_t)(O[sub][nt][rr] * il[rr]);
            }
        }
    }
}

// out projection body: 64x128 tile (m0,n0)
__device__ __forceinline__ void out_body(
    int m0, int n0, const bf16_t* ctxb, const bf16_t* WoT, const float* bo,
    float* out, bf16_t* As, bf16_t* Bs, int tid, int wave, int quad, int l16) {
    const int KD = 1024;
    int wm = wave >> 1, wn = wave & 1;
    int r = tid >> 2;
    int c8 = (((tid & 3) ^ ((tid >> 3) & 3))) * 8;
    const bf16_t* gA  = ctxb + (size_t)(m0 + r) * KD + c8;
    const bf16_t* gB0 = WoT + (size_t)(n0 + r) * KD + c8;
    const bf16_t* gB1 = WoT + (size_t)(n0 + 64 + r) * KD + c8;

    f32x4 acc[2][4];
#pragma unroll
    for (int i = 0; i < 2; i++)
#pragma unroll
        for (int j = 0; j < 4; j++) acc[i][j] = (f32x4){0.f, 0.f, 0.f, 0.f};

    int4 sa = *(const int4*)gA;
    int4 sb0 = *(const int4*)gB0, sb1 = *(const int4*)gB1;
    *(int4*)(As + tid * 8) = sa;
    *(int4*)(Bs + tid * 8) = sb0;
    *(int4*)(Bs + 2048 + tid * 8) = sb1;
    sa = *(const int4*)(gA + 32);
    sb0 = *(const int4*)(gB0 + 32); sb1 = *(const int4*)(gB1 + 32);

    int csw = (quad ^ ((l16 >> 1) & 3)) * 8;
#pragma unroll 1
    for (int kk = 0; kk < 32; kk += 2) {
        barrier_lgkm();
        bf16x8 af[2], bfr[4];
#pragma unroll
        for (int mt = 0; mt < 2; mt++)
            af[mt] = *(const bf16x8*)(As + (wm * 32 + mt * 16 + l16) * 32 + csw);
#pragma unroll
        for (int nt = 0; nt < 4; nt++)
            bfr[nt] = *(const bf16x8*)(Bs + (wn * 64 + nt * 16 + l16) * 32 + csw);
        *(int4*)(As + 2048 + tid * 8) = sa;
        *(int4*)(Bs + 4096 + tid * 8) = sb0;
        *(int4*)(Bs + 6144 + tid * 8) = sb1;
        if (kk + 2 < 32) {
            int k0 = (kk + 2) * 32;
            sa = *(const int4*)(gA + k0);
            sb0 = *(const int4*)(gB0 + k0); sb1 = *(const int4*)(gB1 + k0);
        }
#pragma unroll
        for (int mt = 0; mt < 2; mt++)
#pragma unroll
            for (int nt = 0; nt < 4; nt++)
                acc[mt][nt] = __builtin_amdgcn_mfma_f32_16x16x32_bf16(
                    af[mt], bfr[nt], acc[mt][nt], 0, 0, 0);
        barrier_lgkm();
#pragma unroll
        for (int mt = 0; mt < 2; mt++)
            af[mt] = *(const bf16x8*)(As + 2048 + (wm * 32 + mt * 16 + l16) * 32 + csw);
#pragma unroll
        for (int nt = 0; nt < 4; nt++)
            bfr[nt] = *(const bf16x8*)(Bs + 4096 + (wn * 64 + nt * 16 + l16) * 32 + csw);
        if (kk + 2 < 32) {
            *(int4*)(As + tid * 8) = sa;
            *(int4*)(Bs + tid * 8) = sb0;
            *(int4*)(Bs + 2048 + tid * 8) = sb1;
            if (kk + 3 < 32) {
                int k0 = (kk + 3) * 32;
                sa = *(const int4*)(gA + k0);
                sb0 = *(const int4*)(gB0 + k0); sb1 = *(const int4*)(gB1 + k0);
            }
        }
#pragma unroll
        for (int mt = 0; mt < 2; mt++)
#pragma unroll
            for (int nt = 0; nt < 4; nt++)
                acc[mt][nt] = __builtin_amdgcn_mfma_f32_16x16x32_bf16(
                    af[mt], bfr[nt], acc[mt][nt], 0, 0, 0);
    }

#pragma unroll
    for (int mt = 0; mt < 2; mt++) {
        int mg_base = m0 + wm * 32 + mt * 16 + quad * 4;
#pragma unroll
        for (int nt = 0; nt < 4; nt++) {
            int ng = n0 + wn * 64 + nt * 16 + l16;
            float bv = bo[ng];
#pragma unroll
            for (int rr = 0; rr < 4; rr++) {
                int mg = mg_base + rr;
                out[(size_t)mg * 1024 + ng] = acc[mt][nt][rr] + bv;
            }
        }
    }
}

// ---------------- cooperative mega-kernel ----------------
__global__ __launch_bounds__(256, 2) void mega(
    const float* __restrict__ x, const float* __restrict__ Wq,
    const float* __restrict__ Wk, const float* __restrict__ Wv,
    const float* __restrict__ Wo, const float* __restrict__ bo,
    float* __restrict__ out, char* __restrict__ ws) {
    __shared__ __align__(16) char smem[49152];
    __shared__ int s_job;
    cg::grid_group grid = cg::this_grid();

    int tid = threadIdx.x;
    int wave = tid >> 6, lane = tid & 63;
    int quad = lane >> 4, l16 = lane & 15;
    int blk = blockIdx.x;

    bf16_t* xb   = (bf16_t*)ws;
    bf16_t* WTs  = (bf16_t*)(ws + (8u << 20));
    bf16_t* Qb   = (bf16_t*)(ws + (16u << 20));
    bf16_t* Kb   = (bf16_t*)(ws + (24u << 20));
    bf16_t* Vb   = (bf16_t*)(ws + (32u << 20));
    bf16_t* ctxb = (bf16_t*)(ws + (40u << 20));

    // ---- Phase 0: cvt x; transpose weights; reset queues ----
    if (blk == 0 && tid == 0) { g_j1 = 0; g_j2 = 0; }
    {
        const float4* x4 = (const float4*)x;
        bf16x4* xb4 = (bf16x4*)xb;
#pragma unroll 1
        for (int i = blk * 256 + tid; i < 1048576; i += 512 * 256) {
            float4 v = x4[i];
            bf16x4 o;
            o[0] = (bf16_t)v.x; o[1] = (bf16_t)v.y;
            o[2] = (bf16_t)v.z; o[3] = (bf16_t)v.w;
            xb4[i] = o;
        }
        bf16_t* T = (bf16_t*)smem;  // 64 x 65
#pragma unroll 1
        for (int jj = blk; jj < 1024; jj += 512) {
            int k0 = (jj & 15) * 64, n0 = ((jj >> 4) & 15) * 64, z = jj >> 8;
            const float* W = (z == 0) ? Wq : (z == 1) ? Wk : (z == 2) ? Wv : Wo;
            bf16_t* WT = WTs + (size_t)z * 1048576;
            __syncthreads();
#pragma unroll
            for (int c = 0; c < 4; c++) {
                int idx = c * 256 + tid;
                int row = idx >> 4, col4 = (idx & 15) * 4;
                float4 v = *(const float4*)(W + (k0 + row) * 1024 + n0 + col4);
                T[row * 65 + col4 + 0] = (bf16_t)v.x;
                T[row * 65 + col4 + 1] = (bf16_t)v.y;
                T[row * 65 + col4 + 2] = (bf16_t)v.z;
                T[row * 65 + col4 + 3] = (bf16_t)v.w;
            }
            __syncthreads();
#pragma unroll
            for (int c = 0; c < 4; c++) {
                int idx = c * 256 + tid;
                int nrow = idx >> 4, kc4 = (idx & 15) * 4;
                bf16x4 o;
                o[0] = T[(kc4 + 0) * 65 + nrow];
                o[1] = T[(kc4 + 1) * 65 + nrow];
                o[2] = T[(kc4 + 2) * 65 + nrow];
                o[3] = T[(kc4 + 3) * 65 + nrow];
                *(bf16x4*)(WT + (n0 + nrow) * 1024 + k0 + kc4) = o;
            }
        }
    }
    __threadfence();
    grid.sync();

    // ---- Phase 1: qkv GEMM queue (768 jobs) ----
    {
        bf16_t* As = (bf16_t*)smem;
        bf16_t* Bs = (bf16_t*)(smem + 16384);
#pragma unroll 1
        while (true) {
            __syncthreads();
            if (tid == 0) s_job = atomicAdd(&g_j1, 1);
            __syncthreads();
            int j = s_job;
            if (j >= 768) break;
            qkv_body(j & 31, (j >> 5) & 7, j >> 8, xb, WTs, WTs + 1048576,
                     WTs + 2097152, Qb, Kb, Vb, As, Bs, tid, wave, quad, l16);
        }
    }
    __threadfence();
    grid.sync();

    // ---- Phase 2: attention queue (512 jobs, heavy first) ----
    {
        bf16_t* Ks = (bf16_t*)smem;
        bf16_t* Vs = (bf16_t*)(smem + 16384);
        bf16_t* Ps = (bf16_t*)(smem + 32768);
#pragma unroll 1
        while (true) {
            __syncthreads();
            if (tid == 0) s_job = atomicAdd(&g_j2, 1);
            __syncthreads();
            int j = s_job;
            if (j >= 512) break;
            attn_body(15 - (j >> 5), j & 31, Qb, Kb, Vb, ctxb,
                      Ks, Vs, Ps, tid, wave, quad, l16);
        }
    }
    __threadfence();
    grid.sync();

    // ---- Phase 3: out projection (static 1:1, 512 jobs) ----
    {
        bf16_t* As = (bf16_t*)smem;
        bf16_t* Bs = (bf16_t*)(smem + 8192);
        out_body((blk & 63) * 64, (blk >> 6) * 128, ctxb, WTs + 3145728, bo,
                 out, As, Bs, tid, wave, quad, l16);
    }
}

// ---------------- fallback separate kernels ----------------
__global__ __launch_bounds__(256) void cvt_k(const float* __restrict__ src,
                                             bf16_t* __restrict__ dst) {
    int i = blockIdx.x * 256 + threadIdx.x;
    float4 v = ((const float4*)src)[i];
    bf16x4 o;
    o[0] = (bf16_t)v.x; o[1] = (bf16_t)v.y; o[2] = (bf16_t)v.z; o[3] = (bf16_t)v.w;
    ((bf16x4*)dst)[i] = o;
}

__global__ __launch_bounds__(256) void transpose_k(
    const float* __restrict__ W0, const float* __restrict__ W1,
    const float* __restrict__ W2, const float* __restrict__ W3,
    bf16_t* __restrict__ outbase) {
    __shared__ bf16_t T[64][65];
    int t = threadIdx.x;
    int k0 = blockIdx.x * 64, n0 = blockIdx.y * 64, z = blockIdx.z;
    const float* W = (z == 0) ? W0 : (z == 1) ? W1 : (z == 2) ? W2 : W3;
    bf16_t* WT = outbase + (size_t)z * 1048576;
#pragma unroll
    for (int c = 0; c < 4; c++) {
        int idx = c * 256 + t;
        int row = idx >> 4, col4 = (idx & 15) * 4;
        float4 v = *(const float4*)(W + (k0 + row) * 1024 + n0 + col4);
        T[row][col4 + 0] = (bf16_t)v.x;
        T[row][col4 + 1] = (bf16_t)v.y;
        T[row][col4 + 2] = (bf16_t)v.z;
        T[row][col4 + 3] = (bf16_t)v.w;
    }
    __syncthreads();
#pragma unroll
    for (int c = 0; c < 4; c++) {
        int idx = c * 256 + t;
        int nrow = idx >> 4, kc4 = (idx & 15) * 4;
        bf16x4 o;
        o[0] = T[kc4 + 0][nrow];
        o[1] = T[kc4 + 1][nrow];
        o[2] = T[kc4 + 2][nrow];
        o[3] = T[kc4 + 3][nrow];
        *(bf16x4*)(WT + (n0 + nrow) * 1024 + k0 + kc4) = o;
    }
}

__global__ __launch_bounds__(256) void qkv_k(
    const bf16_t* __restrict__ xb, const bf16_t* __restrict__ WTs,
    bf16_t* __restrict__ Qb, bf16_t* __restrict__ Kb, bf16_t* __restrict__ Vb) {
    __shared__ __align__(16) bf16_t As[2][4096];
    __shared__ __align__(16) bf16_t Bs[2][4096];
    int tid = threadIdx.x, wave = tid >> 6, lane = tid & 63;
    qkv_body(blockIdx.x, blockIdx.y, blockIdx.z, xb, WTs, WTs + 1048576,
             WTs + 2097152, Qb, Kb, Vb, As[0], Bs[0], tid, wave,
             lane >> 4, lane & 15);
}

__global__ __launch_bounds__(256) void attn_k(
    const bf16_t* __restrict__ Qb, const bf16_t* __restrict__ Kb,
    const bf16_t* __restrict__ Vb, bf16_t* __restrict__ ctxb) {
    __shared__ __align__(16) bf16_t Ks[2][4096];
    __shared__ __align__(16) bf16_t Vs[2][4096];
    __shared__ __align__(16) bf16_t Ps[2][4096];
    int tid = threadIdx.x, wave = tid >> 6, lane = tid & 63;
    int f = blockIdx.x + 32 * blockIdx.y;
    int g = f >> 8, s = f & 255;
    int qtj = g ? (15 - (s & 15)) : (s & 15);
    int bh = (s >> 4) + 16 * g;
    attn_body(qtj, bh, Qb, Kb, Vb, ctxb, Ks[0], Vs[0], Ps[0],
              tid, wave, lane >> 4, lane & 15);
}

__global__ __launch_bounds__(256) void out_k(
    const bf16_t* __restrict__ ctxb, const bf16_t* __restrict__ WoT,
    const float* __restrict__ bo, float* __restrict__ out) {
    __shared__ __align__(16) bf16_t As[2][2048];
    __shared__ __align__(16) bf16_t Bs[2][4096];
    int tid = threadIdx.x, wave = tid >> 6, lane = tid & 63;
    out_body(blockIdx.x * 64, blockIdx.y * 128, ctxb, WoT, bo, out,
             As[0], Bs[0], tid, wave, lane >> 4, lane & 15);
}

extern "C" void kernel_launch(void* const* d_in, const int* in_sizes, int n_in,
                              void* d_out, int out_size, void* d_ws, size_t ws_size,
                              hipStream_t stream) {
    const float* x  = (const float*)d_in[0];
    const float* Wq = (const float*)d_in[1];
    const float* Wk = (const float*)d_in[2];
    const float* Wv = (const float*)d_in[3];
    const float* Wo = (const float*)d_in[4];
    const float* bo = (const float*)d_in[5];
    float* out = (float*)d_out;
    char* ws = (char*)d_ws;

    void* kargs[] = {(void*)&x, (void*)&Wq, (void*)&Wk, (void*)&Wv,
                     (void*)&Wo, (void*)&bo, (void*)&out, (void*)&ws};
    hipError_t err = hipLaunchCooperativeKernel((const void*)mega, dim3(512),
                                                dim3(256), kargs, 0, stream);
    if (err != hipSuccess) {
        // fallback: known-good separate-kernel pipeline (r6 qkv + r7 attn)
        bf16_t* xb   = (bf16_t*)ws;
        bf16_t* WTs  = (bf16_t*)(ws + (8u << 20));
        bf16_t* Qb   = (bf16_t*)(ws + (16u << 20));
        bf16_t* Kb   = (bf16_t*)(ws + (24u << 20));
        bf16_t* Vb   = (bf16_t*)(ws + (32u << 20));
        bf16_t* ctxb = (bf16_t*)(ws + (40u << 20));
        cvt_k<<<4096, 256, 0, stream>>>(x, xb);
        transpose_k<<<dim3(16, 16, 4), 256, 0, stream>>>(Wq, Wk, Wv, Wo, WTs);
        qkv_k<<<dim3(32, 8, 3), 256, 0, stream>>>(xb, WTs, Qb, Kb, Vb);
        attn_k<<<dim3(32, 16), 256, 0, stream>>>(Qb, Kb, Vb, ctxb);
        out_k<<<dim3(64, 8), 256, 0, stream>>>(ctxb, WTs + 3145728, bo, out);
    }
}

// Round 10
// 180.416 us; speedup vs baseline: 3.2401x; 3.2401x over previous
//
#include <hip/hip_runtime.h>
#include <hip/hip_bf16.h>

// Round 10: revert cooperative mega (r9: 500us, spill-bound — VGPR 128 < need,
// 100MB scratch traffic). Best-known separate pipeline:
//   prep (fused cvt x + weight transpose, 1 launch)
//   qkv  = r6 register-staged bf16 GEMM (measured 49.8us)
//   attn = r7 128-row dual-subtile, reg-staged K/V, lgkm-only barriers
//   out  = r5/r6 64x128 register-staged GEMM
// All bodies correctness-verified (ran inside r9 mega, absmax 0.015625).

typedef __bf16 bf16_t;
typedef __bf16 bf16x4 __attribute__((ext_vector_type(4)));
typedef __bf16 bf16x8 __attribute__((ext_vector_type(8)));
typedef float f32x4 __attribute__((ext_vector_type(4)));

__device__ __forceinline__ void barrier_lgkm() {
    asm volatile("s_waitcnt lgkmcnt(0)\n\ts_barrier" ::: "memory");
}

__device__ __forceinline__ float exp_pwrite(f32x4 sc[4], bf16_t* Ps,
                                            int wave, int quad, int l16) {
    float part = 0.f;
    int rowbase = (wave * 16 + l16) * 64;
    int gran = (quad & 1) * 4;
    int chi = quad >> 1;
#pragma unroll
    for (int nt = 0; nt < 4; nt++) {
        f32x4 p;
#pragma unroll
        for (int rr = 0; rr < 4; rr++) {
            p[rr] = __builtin_amdgcn_exp2f(sc[nt][rr]);
            part += p[rr];
        }
        bf16x4 pb;
#pragma unroll
        for (int rr = 0; rr < 4; rr++) pb[rr] = (bf16_t)p[rr];
        int cc = (nt * 2 + chi) ^ (l16 & 7);
        *(bf16x4*)(Ps + rowbase + cc * 8 + gran) = pb;
    }
    part += __shfl_xor(part, 16);
    part += __shfl_xor(part, 32);
    return part;
}

// ---------------- prep: fused x cvt + 4x weight transpose ----------------
// blocks 0..4095: cvt chunk; blocks 4096..5119: transpose job (1024 jobs)
__global__ __launch_bounds__(256) void prep_k(
    const float* __restrict__ x, const float* __restrict__ W0,
    const float* __restrict__ W1, const float* __restrict__ W2,
    const float* __restrict__ W3, bf16_t* __restrict__ xb,
    bf16_t* __restrict__ WTs) {
    __shared__ bf16_t T[64][65];
    int t = threadIdx.x;
    int blk = blockIdx.x;
    if (blk < 4096) {
        int i = blk * 256 + t;
        float4 v = ((const float4*)x)[i];
        bf16x4 o;
        o[0] = (bf16_t)v.x; o[1] = (bf16_t)v.y;
        o[2] = (bf16_t)v.z; o[3] = (bf16_t)v.w;
        ((bf16x4*)xb)[i] = o;
        return;
    }
    int jj = blk - 4096;
    int k0 = (jj & 15) * 64, n0 = ((jj >> 4) & 15) * 64, z = jj >> 8;
    const float* W = (z == 0) ? W0 : (z == 1) ? W1 : (z == 2) ? W2 : W3;
    bf16_t* WT = WTs + (size_t)z * 1048576;
#pragma unroll
    for (int c = 0; c < 4; c++) {
        int idx = c * 256 + t;
        int row = idx >> 4, col4 = (idx & 15) * 4;
        float4 v = *(const float4*)(W + (k0 + row) * 1024 + n0 + col4);
        T[row][col4 + 0] = (bf16_t)v.x;
        T[row][col4 + 1] = (bf16_t)v.y;
        T[row][col4 + 2] = (bf16_t)v.z;
        T[row][col4 + 3] = (bf16_t)v.w;
    }
    __syncthreads();
#pragma unroll
    for (int c = 0; c < 4; c++) {
        int idx = c * 256 + t;
        int nrow = idx >> 4, kc4 = (idx & 15) * 4;
        bf16x4 o;
        o[0] = T[kc4 + 0][nrow];
        o[1] = T[kc4 + 1][nrow];
        o[2] = T[kc4 + 2][nrow];
        o[3] = T[kc4 + 3][nrow];
        *(bf16x4*)(WT + (n0 + nrow) * 1024 + k0 + kc4) = o;
    }
}

// ---------------- qkv GEMM (r6 body) ----------------
// z=0: Q natural [B,H,S,64]
// z=1: K tiled-swizzled per (b,h): [kt][row=s%64][chunk^(row%8)][d%8]
// z=2: V^T tiled-swizzled per (b,h): [kt][d][chunk^(d%8)][s%8]
__global__ __launch_bounds__(256) void qkv_k(
    const bf16_t* __restrict__ xb, const bf16_t* __restrict__ WTs,
    bf16_t* __restrict__ Qb, bf16_t* __restrict__ Kb, bf16_t* __restrict__ Vb) {
    const int KD = 1024;
    __shared__ __align__(16) bf16_t As[2][4096];
    __shared__ __align__(16) bf16_t Bs[2][4096];
    int tid = threadIdx.x;
    int wave = tid >> 6, lane = tid & 63;
    int quad = lane >> 4, l16 = lane & 15;
    int wm = wave >> 1, wn = wave & 1;
    int z = blockIdx.z;
    const bf16_t* BT = WTs + (size_t)z * 1048576;
    int m0 = blockIdx.x * 128;
    int n0 = blockIdx.y * 128;

    int r = tid >> 2;
    int c8 = (((tid & 3) ^ ((tid >> 3) & 3))) * 8;
    const bf16_t* gA0 = xb + (size_t)(m0 + r) * KD + c8;
    const bf16_t* gA1 = xb + (size_t)(m0 + 64 + r) * KD + c8;
    const bf16_t* gB0 = BT + (size_t)(n0 + r) * KD + c8;
    const bf16_t* gB1 = BT + (size_t)(n0 + 64 + r) * KD + c8;

    f32x4 acc[4][4];
#pragma unroll
    for (int i = 0; i < 4; i++)
#pragma unroll
        for (int j = 0; j < 4; j++) acc[i][j] = (f32x4){0.f, 0.f, 0.f, 0.f};

    int4 sa0 = *(const int4*)gA0, sa1 = *(const int4*)gA1;
    int4 sb0 = *(const int4*)gB0, sb1 = *(const int4*)gB1;
    *(int4*)(As[0] + tid * 8) = sa0;
    *(int4*)(As[0] + 2048 + tid * 8) = sa1;
    *(int4*)(Bs[0] + tid * 8) = sb0;
    *(int4*)(Bs[0] + 2048 + tid * 8) = sb1;
    sa0 = *(const int4*)(gA0 + 32); sa1 = *(const int4*)(gA1 + 32);
    sb0 = *(const int4*)(gB0 + 32); sb1 = *(const int4*)(gB1 + 32);

    int csw = (quad ^ ((l16 >> 1) & 3)) * 8;
#pragma unroll 1
    for (int kk = 0; kk < 32; kk += 2) {
        barrier_lgkm();
        bf16x8 af[4], bfr[4];
#pragma unroll
        for (int mt = 0; mt < 4; mt++)
            af[mt] = *(const bf16x8*)(As[0] + (wm * 64 + mt * 16 + l16) * 32 + csw);
#pragma unroll
        for (int nt = 0; nt < 4; nt++)
            bfr[nt] = *(const bf16x8*)(Bs[0] + (wn * 64 + nt * 16 + l16) * 32 + csw);
        *(int4*)(As[1] + tid * 8) = sa0;
        *(int4*)(As[1] + 2048 + tid * 8) = sa1;
        *(int4*)(Bs[1] + tid * 8) = sb0;
        *(int4*)(Bs[1] + 2048 + tid * 8) = sb1;
        if (kk + 2 < 32) {
            int k0 = (kk + 2) * 32;
            sa0 = *(const int4*)(gA0 + k0); sa1 = *(const int4*)(gA1 + k0);
            sb0 = *(const int4*)(gB0 + k0); sb1 = *(const int4*)(gB1 + k0);
        }
        if (z == 2) {
#pragma unroll
            for (int mt = 0; mt < 4; mt++)
#pragma unroll
                for (int nt = 0; nt < 4; nt++)
                    acc[mt][nt] = __builtin_amdgcn_mfma_f32_16x16x32_bf16(
                        bfr[nt], af[mt], acc[mt][nt], 0, 0, 0);
        } else {
#pragma unroll
            for (int mt = 0; mt < 4; mt++)
#pragma unroll
                for (int nt = 0; nt < 4; nt++)
                    acc[mt][nt] = __builtin_amdgcn_mfma_f32_16x16x32_bf16(
                        af[mt], bfr[nt], acc[mt][nt], 0, 0, 0);
        }
        barrier_lgkm();
#pragma unroll
        for (int mt = 0; mt < 4; mt++)
            af[mt] = *(const bf16x8*)(As[1] + (wm * 64 + mt * 16 + l16) * 32 + csw);
#pragma unroll
        for (int nt = 0; nt < 4; nt++)
            bfr[nt] = *(const bf16x8*)(Bs[1] + (wn * 64 + nt * 16 + l16) * 32 + csw);
        if (kk + 2 < 32) {
            *(int4*)(As[0] + tid * 8) = sa0;
            *(int4*)(As[0] + 2048 + tid * 8) = sa1;
            *(int4*)(Bs[0] + tid * 8) = sb0;
            *(int4*)(Bs[0] + 2048 + tid * 8) = sb1;
            if (kk + 3 < 32) {
                int k0 = (kk + 3) * 32;
                sa0 = *(const int4*)(gA0 + k0); sa1 = *(const int4*)(gA1 + k0);
                sb0 = *(const int4*)(gB0 + k0); sb1 = *(const int4*)(gB1 + k0);
            }
        }
        if (z == 2) {
#pragma unroll
            for (int mt = 0; mt < 4; mt++)
#pragma unroll
                for (int nt = 0; nt < 4; nt++)
                    acc[mt][nt] = __builtin_amdgcn_mfma_f32_16x16x32_bf16(
                        bfr[nt], af[mt], acc[mt][nt], 0, 0, 0);
        } else {
#pragma unroll
            for (int mt = 0; mt < 4; mt++)
#pragma unroll
                for (int nt = 0; nt < 4; nt++)
                    acc[mt][nt] = __builtin_amdgcn_mfma_f32_16x16x32_bf16(
                        af[mt], bfr[nt], acc[mt][nt], 0, 0, 0);
        }
    }

    if (z == 0) {
#pragma unroll
        for (int mt = 0; mt < 4; mt++) {
            int mg_base = m0 + wm * 64 + mt * 16 + quad * 4;
#pragma unroll
            for (int nt = 0; nt < 4; nt++) {
                int ng = n0 + wn * 64 + nt * 16 + l16;
                int h = ng >> 6, d = ng & 63;
#pragma unroll
                for (int rr = 0; rr < 4; rr++) {
                    int mg = mg_base + rr;
                    int b = mg >> 11, s = mg & 2047;
                    Qb[(((size_t)(b * 16 + h) * 2048) + s) * 64 + d] =
                        (bf16_t)acc[mt][nt][rr];
                }
            }
        }
    } else if (z == 1) {
#pragma unroll
        for (int mt = 0; mt < 4; mt++) {
            int mg_base = m0 + wm * 64 + mt * 16 + quad * 4;
#pragma unroll
            for (int nt = 0; nt < 4; nt++) {
                int ng = n0 + wn * 64 + nt * 16 + l16;
                int h = ng >> 6, dd = ng & 63;
#pragma unroll
                for (int rr = 0; rr < 4; rr++) {
                    int mg = mg_base + rr;
                    int b = mg >> 11, sl = mg & 2047;
                    int kt = sl >> 6, row = sl & 63;
                    int cc = (dd >> 3) ^ (row & 7);
                    Kb[(size_t)(b * 16 + h) * 131072 + kt * 4096 + row * 64 +
                       cc * 8 + (dd & 7)] = (bf16_t)acc[mt][nt][rr];
                }
            }
        }
    } else {
#pragma unroll
        for (int mt = 0; mt < 4; mt++) {
            int sg = m0 + wm * 64 + mt * 16 + l16;
            int b = sg >> 11, sl = sg & 2047;
            int kt = sl >> 6, srow = sl & 63;
#pragma unroll
            for (int nt = 0; nt < 4; nt++) {
                int dg_base = n0 + wn * 64 + nt * 16 + quad * 4;
#pragma unroll
                for (int rr = 0; rr < 4; rr++) {
                    int dg = dg_base + rr;
                    int h = dg >> 6, dd = dg & 63;
                    int cc = (srow >> 3) ^ (dd & 7);
                    Vb[(size_t)(b * 16 + h) * 131072 + kt * 4096 + dd * 64 +
                       cc * 8 + (srow & 7)] = (bf16_t)acc[mt][nt][rr];
                }
            }
        }
    }
}

// ---------------- attention (r7 body: 128 q-rows, reg-staged) ----------------
__global__ __launch_bounds__(256) void attn_k(
    const bf16_t* __restrict__ Qb, const bf16_t* __restrict__ Kb,
    const bf16_t* __restrict__ Vb, bf16_t* __restrict__ ctxb) {
    const int S = 2048;
    __shared__ __align__(16) bf16_t Ks[2][4096];
    __shared__ __align__(16) bf16_t Vs[2][4096];
    __shared__ __align__(16) bf16_t Ps[2][4096];
    int tid = threadIdx.x, wave = tid >> 6, lane = tid & 63;
    int quad = lane >> 4, l16 = lane & 15;

    int f = blockIdx.x + 32 * blockIdx.y;
    int g = f >> 8, s = f & 255;
    int qtj = g ? (15 - (s & 15)) : (s & 15);
    int bh = (s >> 4) + 16 * g;
    int h = bh & 15, b = bh >> 4;
    int q0 = qtj * 128;

    const bf16_t* Qbh = Qb + (size_t)bh * S * 64;
    const bf16_t* Kbh = Kb + (size_t)bh * 131072;
    const bf16_t* Vbh = Vb + (size_t)bh * 131072;

    const float qs = 0.125f * 1.44269504f;
    bf16x8 aQ[2][2];
#pragma unroll
    for (int sub = 0; sub < 2; sub++) {
        const bf16_t* rq = Qbh + (size_t)(q0 + sub * 64 + wave * 16 + l16) * 64;
#pragma unroll
        for (int ks = 0; ks < 2; ks++) {
            bf16x8 t = *(const bf16x8*)(rq + ks * 32 + quad * 8);
#pragma unroll
            for (int j = 0; j < 8; j++) t[j] = (bf16_t)((float)t[j] * qs);
            aQ[sub][ks] = t;
        }
    }

    float L[2] = {0.f, 0.f};
    f32x4 O[2][4];
#pragma unroll
    for (int sub = 0; sub < 2; sub++)
#pragma unroll
        for (int i = 0; i < 4; i++) O[sub][i] = (f32x4){0.f, 0.f, 0.f, 0.f};

    int tmax = 2 * qtj + 2;
    int4 ska = *(const int4*)(Kbh + tid * 8);
    int4 skb = *(const int4*)(Kbh + 2048 + tid * 8);
    int4 sva = *(const int4*)(Vbh + tid * 8);
    int4 svb = *(const int4*)(Vbh + 2048 + tid * 8);
    *(int4*)(Ks[0] + tid * 8) = ska; *(int4*)(Ks[0] + 2048 + tid * 8) = skb;
    *(int4*)(Vs[0] + tid * 8) = sva; *(int4*)(Vs[0] + 2048 + tid * 8) = svb;
    ska = *(const int4*)(Kbh + 4096 + tid * 8);
    skb = *(const int4*)(Kbh + 6144 + tid * 8);
    sva = *(const int4*)(Vbh + 4096 + tid * 8);
    svb = *(const int4*)(Vbh + 6144 + tid * 8);

#pragma unroll 1
    for (int kt = 0; kt < tmax; kt++) {
        int cur = kt & 1;
        barrier_lgkm();
        bf16x8 kf[4][2], vf[4][2];
#pragma unroll
        for (int nt = 0; nt < 4; nt++) {
            const bf16_t* krow = Ks[cur] + (nt * 16 + l16) * 64;
            const bf16_t* vrow = Vs[cur] + (nt * 16 + l16) * 64;
#pragma unroll
            for (int ks = 0; ks < 2; ks++) {
                int csw = ((ks * 4 + quad) ^ (l16 & 7)) * 8;
                kf[nt][ks] = *(const bf16x8*)(krow + csw);
                vf[nt][ks] = *(const bf16x8*)(vrow + csw);
            }
        }
        if (kt + 1 < tmax) {
            *(int4*)(Ks[cur ^ 1] + tid * 8) = ska;
            *(int4*)(Ks[cur ^ 1] + 2048 + tid * 8) = skb;
            *(int4*)(Vs[cur ^ 1] + tid * 8) = sva;
            *(int4*)(Vs[cur ^ 1] + 2048 + tid * 8) = svb;
        }
        if (kt + 2 < tmax) {
            const bf16_t* kg = Kbh + (kt + 2) * 4096;
            const bf16_t* vg = Vbh + (kt + 2) * 4096;
            ska = *(const int4*)(kg + tid * 8);
            skb = *(const int4*)(kg + 2048 + tid * 8);
            sva = *(const int4*)(vg + tid * 8);
            svb = *(const int4*)(vg + 2048 + tid * 8);
        }

        bool do_lo = (kt < tmax - 1);
        if (do_lo) {
            f32x4 sc[4];
#pragma unroll
            for (int nt = 0; nt < 4; nt++) {
                f32x4 ss = (f32x4){0.f, 0.f, 0.f, 0.f};
                ss = __builtin_amdgcn_mfma_f32_16x16x32_bf16(kf[nt][0], aQ[0][0], ss, 0, 0, 0);
                ss = __builtin_amdgcn_mfma_f32_16x16x32_bf16(kf[nt][1], aQ[0][1], ss, 0, 0, 0);
                sc[nt] = ss;
            }
            if (kt == tmax - 2) {
                int qg = q0 + wave * 16 + l16;
#pragma unroll
                for (int nt = 0; nt < 4; nt++)
#pragma unroll
                    for (int rr = 0; rr < 4; rr++)
                        if (kt * 64 + nt * 16 + quad * 4 + rr > qg) sc[nt][rr] = -1e30f;
            }
            L[0] += exp_pwrite(sc, Ps[0], wave, quad, l16);
        }
        {
            f32x4 sc[4];
#pragma unroll
            for (int nt = 0; nt < 4; nt++) {
                f32x4 ss = (f32x4){0.f, 0.f, 0.f, 0.f};
                ss = __builtin_amdgcn_mfma_f32_16x16x32_bf16(kf[nt][0], aQ[1][0], ss, 0, 0, 0);
                ss = __builtin_amdgcn_mfma_f32_16x16x32_bf16(kf[nt][1], aQ[1][1], ss, 0, 0, 0);
                sc[nt] = ss;
            }
            if (kt == tmax - 1) {
                int qg = q0 + 64 + wave * 16 + l16;
#pragma unroll
                for (int nt = 0; nt < 4; nt++)
#pragma unroll
                    for (int rr = 0; rr < 4; rr++)
                        if (kt * 64 + nt * 16 + quad * 4 + rr > qg) sc[nt][rr] = -1e30f;
            }
            L[1] += exp_pwrite(sc, Ps[1], wave, quad, l16);
        }

#pragma unroll
        for (int ks = 0; ks < 2; ks++) {
            int csw = ((ks * 4 + quad) ^ (l16 & 7)) * 8;
            bf16x8 aPhi = *(const bf16x8*)(Ps[1] + (wave * 16 + l16) * 64 + csw);
            bf16x8 aPlo;
            if (do_lo) aPlo = *(const bf16x8*)(Ps[0] + (wave * 16 + l16) * 64 + csw);
#pragma unroll
            for (int nt = 0; nt < 4; nt++) {
                O[1][nt] = __builtin_amdgcn_mfma_f32_16x16x32_bf16(aPhi, vf[nt][ks],
                                                                   O[1][nt], 0, 0, 0);
                if (do_lo)
                    O[0][nt] = __builtin_amdgcn_mfma_f32_16x16x32_bf16(aPlo, vf[nt][ks],
                                                                       O[0][nt], 0, 0, 0);
            }
        }
    }

#pragma unroll
    for (int sub = 0; sub < 2; sub++) {
        float il[4];
#pragma unroll
        for (int rr = 0; rr < 4; rr++) il[rr] = 1.f / __shfl(L[sub], quad * 4 + rr);
#pragma unroll
        for (int nt = 0; nt < 4; nt++) {
#pragma unroll
            for (int rr = 0; rr < 4; rr++) {
                int qoff = q0 + sub * 64 + wave * 16 + quad * 4 + rr;
                int col = h * 64 + nt * 16 + l16;
                ctxb[(size_t)(b * 2048 + qoff) * 1024 + col] =
                    (bf16_t)(O[sub][nt][rr] * il[rr]);
            }
        }
    }
}

// ---------------- out projection (r6 body, 64x128) ----------------
__global__ __launch_bounds__(256) void out_k(
    const bf16_t* __restrict__ ctxb, const bf16_t* __restrict__ WoT,
    const float* __restrict__ bo, float* __restrict__ out) {
    const int KD = 1024;
    __shared__ __align__(16) bf16_t As[2][2048];
    __shared__ __align__(16) bf16_t Bs[2][4096];
    int tid = threadIdx.x;
    int wave = tid >> 6, lane = tid & 63;
    int quad = lane >> 4, l16 = lane & 15;
    int wm = wave >> 1, wn = wave & 1;
    int m0 = blockIdx.x * 64;
    int n0 = blockIdx.y * 128;

    int r = tid >> 2;
    int c8 = (((tid & 3) ^ ((tid >> 3) & 3))) * 8;
    const bf16_t* gA  = ctxb + (size_t)(m0 + r) * KD + c8;
    const bf16_t* gB0 = WoT + (size_t)(n0 + r) * KD + c8;
    const bf16_t* gB1 = WoT + (size_t)(n0 + 64 + r) * KD + c8;

    f32x4 acc[2][4];
#pragma unroll
    for (int i = 0; i < 2; i++)
#pragma unroll
        for (int j = 0; j < 4; j++) acc[i][j] = (f32x4){0.f, 0.f, 0.f, 0.f};

    int4 sa = *(const int4*)gA;
    int4 sb0 = *(const int4*)gB0, sb1 = *(const int4*)gB1;
    *(int4*)(As[0] + tid * 8) = sa;
    *(int4*)(Bs[0] + tid * 8) = sb0;
    *(int4*)(Bs[0] + 2048 + tid * 8) = sb1;
    sa = *(const int4*)(gA + 32);
    sb0 = *(const int4*)(gB0 + 32); sb1 = *(const int4*)(gB1 + 32);

    int csw = (quad ^ ((l16 >> 1) & 3)) * 8;
#pragma unroll 1
    for (int kk = 0; kk < 32; kk += 2) {
        barrier_lgkm();
        bf16x8 af[2], bfr[4];
#pragma unroll
        for (int mt = 0; mt < 2; mt++)
            af[mt] = *(const bf16x8*)(As[0] + (wm * 32 + mt * 16 + l16) * 32 + csw);
#pragma unroll
        for (int nt = 0; nt < 4; nt++)
            bfr[nt] = *(const bf16x8*)(Bs[0] + (wn * 64 + nt * 16 + l16) * 32 + csw);
        *(int4*)(As[1] + tid * 8) = sa;
        *(int4*)(Bs[1] + tid * 8) = sb0;
        *(int4*)(Bs[1] + 2048 + tid * 8) = sb1;
        if (kk + 2 < 32) {
            int k0 = (kk + 2) * 32;
            sa = *(const int4*)(gA + k0);
            sb0 = *(const int4*)(gB0 + k0); sb1 = *(const int4*)(gB1 + k0);
        }
#pragma unroll
        for (int mt = 0; mt < 2; mt++)
#pragma unroll
            for (int nt = 0; nt < 4; nt++)
                acc[mt][nt] = __builtin_amdgcn_mfma_f32_16x16x32_bf16(
                    af[mt], bfr[nt], acc[mt][nt], 0, 0, 0);
        barrier_lgkm();
#pragma unroll
        for (int mt = 0; mt < 2; mt++)
            af[mt] = *(const bf16x8*)(As[1] + (wm * 32 + mt * 16 + l16) * 32 + csw);
#pragma unroll
        for (int nt = 0; nt < 4; nt++)
            bfr[nt] = *(const bf16x8*)(Bs[1] + (wn * 64 + nt * 16 + l16) * 32 + csw);
        if (kk + 2 < 32) {
            *(int4*)(As[0] + tid * 8) = sa;
            *(int4*)(Bs[0] + tid * 8) = sb0;
            *(int4*)(Bs[0] + 2048 + tid * 8) = sb1;
            if (kk + 3 < 32) {
                int k0 = (kk + 3) * 32;
                sa = *(const int4*)(gA + k0);
                sb0 = *(const int4*)(gB0 + k0); sb1 = *(const int4*)(gB1 + k0);
            }
        }
#pragma unroll
        for (int mt = 0; mt < 2; mt++)
#pragma unroll
            for (int nt = 0; nt < 4; nt++)
                acc[mt][nt] = __builtin_amdgcn_mfma_f32_16x16x32_bf16(
                    af[mt], bfr[nt], acc[mt][nt], 0, 0, 0);
    }

#pragma unroll
    for (int mt = 0; mt < 2; mt++) {
        int mg_base = m0 + wm * 32 + mt * 16 + quad * 4;
#pragma unroll
        for (int nt = 0; nt < 4; nt++) {
            int ng = n0 + wn * 64 + nt * 16 + l16;
            float bv = bo[ng];
#pragma unroll
            for (int rr = 0; rr < 4; rr++) {
                int mg = mg_base + rr;
                out[(size_t)mg * 1024 + ng] = acc[mt][nt][rr] + bv;
            }
        }
    }
}

extern "C" void kernel_launch(void* const* d_in, const int* in_sizes, int n_in,
                              void* d_out, int out_size, void* d_ws, size_t ws_size,
                              hipStream_t stream) {
    const float* x  = (const float*)d_in[0];
    const float* Wq = (const float*)d_in[1];
    const float* Wk = (const float*)d_in[2];
    const float* Wv = (const float*)d_in[3];
    const float* Wo = (const float*)d_in[4];
    const float* bo = (const float*)d_in[5];
    float* out = (float*)d_out;
    char* ws = (char*)d_ws;

    bf16_t* xb   = (bf16_t*)ws;                  // 8 MB
    bf16_t* WTs  = (bf16_t*)(ws + (8u << 20));   // 4x2 MB
    bf16_t* Qb   = (bf16_t*)(ws + (16u << 20));  // 8 MB natural
    bf16_t* Kb   = (bf16_t*)(ws + (24u << 20));  // 8 MB tiled-swizzled
    bf16_t* Vb   = (bf16_t*)(ws + (32u << 20));  // 8 MB tiled-swizzled V^T
    bf16_t* ctxb = (bf16_t*)(ws + (40u << 20));  // 8 MB

    prep_k<<<5120, 256, 0, stream>>>(x, Wq, Wk, Wv, Wo, xb, WTs);
    qkv_k<<<dim3(32, 8, 3), 256, 0, stream>>>(xb, WTs, Qb, Kb, Vb);
    attn_k<<<dim3(32, 16), 256, 0, stream>>>(Qb, Kb, Vb, ctxb);
    out_k<<<dim3(64, 8), 256, 0, stream>>>(ctxb, WTs + 3145728, bo, out);
}

// Round 11
// 177.663 us; speedup vs baseline: 3.2903x; 1.0155x over previous
//
#include <hip/hip_runtime.h>
#include <hip/hip_bf16.h>

// Round 11: attn without K/V LDS.
// Kb/Vb tiles are fragment-ordered in global memory (qkv epilogue), so each
// wave's kf/vf fragments are coalesced 16B global loads (a wave tiles a 1KB
// region). -> no staging, no double buffer, NO barriers (only the per-wave Ps
// slab stays in LDS; wave-local LDS is in-order). K/V re-reads (4x) are served
// by per-XCD L2: bh is pinned to blockIdx%8 (4 bh x 512KB = 2MB < 4MB L2/XCD).
// Balanced causal pairing kept (co-resident f,f+256 -> qtj q and 15-q).
// prep/qkv/out unchanged from round 10.

typedef __bf16 bf16_t;
typedef __bf16 bf16x4 __attribute__((ext_vector_type(4)));
typedef __bf16 bf16x8 __attribute__((ext_vector_type(8)));
typedef float f32x4 __attribute__((ext_vector_type(4)));

__device__ __forceinline__ void barrier_lgkm() {
    asm volatile("s_waitcnt lgkmcnt(0)\n\ts_barrier" ::: "memory");
}

__device__ __forceinline__ float exp_pwrite(f32x4 sc[4], bf16_t* Ps,
                                            int wave, int quad, int l16) {
    float part = 0.f;
    int rowbase = (wave * 16 + l16) * 64;
    int gran = (quad & 1) * 4;
    int chi = quad >> 1;
#pragma unroll
    for (int nt = 0; nt < 4; nt++) {
        f32x4 p;
#pragma unroll
        for (int rr = 0; rr < 4; rr++) {
            p[rr] = __builtin_amdgcn_exp2f(sc[nt][rr]);
            part += p[rr];
        }
        bf16x4 pb;
#pragma unroll
        for (int rr = 0; rr < 4; rr++) pb[rr] = (bf16_t)p[rr];
        int cc = (nt * 2 + chi) ^ (l16 & 7);
        *(bf16x4*)(Ps + rowbase + cc * 8 + gran) = pb;
    }
    part += __shfl_xor(part, 16);
    part += __shfl_xor(part, 32);
    return part;
}

// ---------------- prep: fused x cvt + 4x weight transpose ----------------
__global__ __launch_bounds__(256) void prep_k(
    const float* __restrict__ x, const float* __restrict__ W0,
    const float* __restrict__ W1, const float* __restrict__ W2,
    const float* __restrict__ W3, bf16_t* __restrict__ xb,
    bf16_t* __restrict__ WTs) {
    __shared__ bf16_t T[64][65];
    int t = threadIdx.x;
    int blk = blockIdx.x;
    if (blk < 4096) {
        int i = blk * 256 + t;
        float4 v = ((const float4*)x)[i];
        bf16x4 o;
        o[0] = (bf16_t)v.x; o[1] = (bf16_t)v.y;
        o[2] = (bf16_t)v.z; o[3] = (bf16_t)v.w;
        ((bf16x4*)xb)[i] = o;
        return;
    }
    int jj = blk - 4096;
    int k0 = (jj & 15) * 64, n0 = ((jj >> 4) & 15) * 64, z = jj >> 8;
    const float* W = (z == 0) ? W0 : (z == 1) ? W1 : (z == 2) ? W2 : W3;
    bf16_t* WT = WTs + (size_t)z * 1048576;
#pragma unroll
    for (int c = 0; c < 4; c++) {
        int idx = c * 256 + t;
        int row = idx >> 4, col4 = (idx & 15) * 4;
        float4 v = *(const float4*)(W + (k0 + row) * 1024 + n0 + col4);
        T[row][col4 + 0] = (bf16_t)v.x;
        T[row][col4 + 1] = (bf16_t)v.y;
        T[row][col4 + 2] = (bf16_t)v.z;
        T[row][col4 + 3] = (bf16_t)v.w;
    }
    __syncthreads();
#pragma unroll
    for (int c = 0; c < 4; c++) {
        int idx = c * 256 + t;
        int nrow = idx >> 4, kc4 = (idx & 15) * 4;
        bf16x4 o;
        o[0] = T[kc4 + 0][nrow];
        o[1] = T[kc4 + 1][nrow];
        o[2] = T[kc4 + 2][nrow];
        o[3] = T[kc4 + 3][nrow];
        *(bf16x4*)(WT + (n0 + nrow) * 1024 + k0 + kc4) = o;
    }
}

// ---------------- qkv GEMM (r6 body, unchanged) ----------------
__global__ __launch_bounds__(256) void qkv_k(
    const bf16_t* __restrict__ xb, const bf16_t* __restrict__ WTs,
    bf16_t* __restrict__ Qb, bf16_t* __restrict__ Kb, bf16_t* __restrict__ Vb) {
    const int KD = 1024;
    __shared__ __align__(16) bf16_t As[2][4096];
    __shared__ __align__(16) bf16_t Bs[2][4096];
    int tid = threadIdx.x;
    int wave = tid >> 6, lane = tid & 63;
    int quad = lane >> 4, l16 = lane & 15;
    int wm = wave >> 1, wn = wave & 1;
    int z = blockIdx.z;
    const bf16_t* BT = WTs + (size_t)z * 1048576;
    int m0 = blockIdx.x * 128;
    int n0 = blockIdx.y * 128;

    int r = tid >> 2;
    int c8 = (((tid & 3) ^ ((tid >> 3) & 3))) * 8;
    const bf16_t* gA0 = xb + (size_t)(m0 + r) * KD + c8;
    const bf16_t* gA1 = xb + (size_t)(m0 + 64 + r) * KD + c8;
    const bf16_t* gB0 = BT + (size_t)(n0 + r) * KD + c8;
    const bf16_t* gB1 = BT + (size_t)(n0 + 64 + r) * KD + c8;

    f32x4 acc[4][4];
#pragma unroll
    for (int i = 0; i < 4; i++)
#pragma unroll
        for (int j = 0; j < 4; j++) acc[i][j] = (f32x4){0.f, 0.f, 0.f, 0.f};

    int4 sa0 = *(const int4*)gA0, sa1 = *(const int4*)gA1;
    int4 sb0 = *(const int4*)gB0, sb1 = *(const int4*)gB1;
    *(int4*)(As[0] + tid * 8) = sa0;
    *(int4*)(As[0] + 2048 + tid * 8) = sa1;
    *(int4*)(Bs[0] + tid * 8) = sb0;
    *(int4*)(Bs[0] + 2048 + tid * 8) = sb1;
    sa0 = *(const int4*)(gA0 + 32); sa1 = *(const int4*)(gA1 + 32);
    sb0 = *(const int4*)(gB0 + 32); sb1 = *(const int4*)(gB1 + 32);

    int csw = (quad ^ ((l16 >> 1) & 3)) * 8;
#pragma unroll 1
    for (int kk = 0; kk < 32; kk += 2) {
        barrier_lgkm();
        bf16x8 af[4], bfr[4];
#pragma unroll
        for (int mt = 0; mt < 4; mt++)
            af[mt] = *(const bf16x8*)(As[0] + (wm * 64 + mt * 16 + l16) * 32 + csw);
#pragma unroll
        for (int nt = 0; nt < 4; nt++)
            bfr[nt] = *(const bf16x8*)(Bs[0] + (wn * 64 + nt * 16 + l16) * 32 + csw);
        *(int4*)(As[1] + tid * 8) = sa0;
        *(int4*)(As[1] + 2048 + tid * 8) = sa1;
        *(int4*)(Bs[1] + tid * 8) = sb0;
        *(int4*)(Bs[1] + 2048 + tid * 8) = sb1;
        if (kk + 2 < 32) {
            int k0 = (kk + 2) * 32;
            sa0 = *(const int4*)(gA0 + k0); sa1 = *(const int4*)(gA1 + k0);
            sb0 = *(const int4*)(gB0 + k0); sb1 = *(const int4*)(gB1 + k0);
        }
        if (z == 2) {
#pragma unroll
            for (int mt = 0; mt < 4; mt++)
#pragma unroll
                for (int nt = 0; nt < 4; nt++)
                    acc[mt][nt] = __builtin_amdgcn_mfma_f32_16x16x32_bf16(
                        bfr[nt], af[mt], acc[mt][nt], 0, 0, 0);
        } else {
#pragma unroll
            for (int mt = 0; mt < 4; mt++)
#pragma unroll
                for (int nt = 0; nt < 4; nt++)
                    acc[mt][nt] = __builtin_amdgcn_mfma_f32_16x16x32_bf16(
                        af[mt], bfr[nt], acc[mt][nt], 0, 0, 0);
        }
        barrier_lgkm();
#pragma unroll
        for (int mt = 0; mt < 4; mt++)
            af[mt] = *(const bf16x8*)(As[1] + (wm * 64 + mt * 16 + l16) * 32 + csw);
#pragma unroll
        for (int nt = 0; nt < 4; nt++)
            bfr[nt] = *(const bf16x8*)(Bs[1] + (wn * 64 + nt * 16 + l16) * 32 + csw);
        if (kk + 2 < 32) {
            *(int4*)(As[0] + tid * 8) = sa0;
            *(int4*)(As[0] + 2048 + tid * 8) = sa1;
            *(int4*)(Bs[0] + tid * 8) = sb0;
            *(int4*)(Bs[0] + 2048 + tid * 8) = sb1;
            if (kk + 3 < 32) {
                int k0 = (kk + 3) * 32;
                sa0 = *(const int4*)(gA0 + k0); sa1 = *(const int4*)(gA1 + k0);
                sb0 = *(const int4*)(gB0 + k0); sb1 = *(const int4*)(gB1 + k0);
            }
        }
        if (z == 2) {
#pragma unroll
            for (int mt = 0; mt < 4; mt++)
#pragma unroll
                for (int nt = 0; nt < 4; nt++)
                    acc[mt][nt] = __builtin_amdgcn_mfma_f32_16x16x32_bf16(
                        bfr[nt], af[mt], acc[mt][nt], 0, 0, 0);
        } else {
#pragma unroll
            for (int mt = 0; mt < 4; mt++)
#pragma unroll
                for (int nt = 0; nt < 4; nt++)
                    acc[mt][nt] = __builtin_amdgcn_mfma_f32_16x16x32_bf16(
                        af[mt], bfr[nt], acc[mt][nt], 0, 0, 0);
        }
    }

    if (z == 0) {
#pragma unroll
        for (int mt = 0; mt < 4; mt++) {
            int mg_base = m0 + wm * 64 + mt * 16 + quad * 4;
#pragma unroll
            for (int nt = 0; nt < 4; nt++) {
                int ng = n0 + wn * 64 + nt * 16 + l16;
                int h = ng >> 6, d = ng & 63;
#pragma unroll
                for (int rr = 0; rr < 4; rr++) {
                    int mg = mg_base + rr;
                    int b = mg >> 11, s = mg & 2047;
                    Qb[(((size_t)(b * 16 + h) * 2048) + s) * 64 + d] =
                        (bf16_t)acc[mt][nt][rr];
                }
            }
        }
    } else if (z == 1) {
#pragma unroll
        for (int mt = 0; mt < 4; mt++) {
            int mg_base = m0 + wm * 64 + mt * 16 + quad * 4;
#pragma unroll
            for (int nt = 0; nt < 4; nt++) {
                int ng = n0 + wn * 64 + nt * 16 + l16;
                int h = ng >> 6, dd = ng & 63;
#pragma unroll
                for (int rr = 0; rr < 4; rr++) {
                    int mg = mg_base + rr;
                    int b = mg >> 11, sl = mg & 2047;
                    int kt = sl >> 6, row = sl & 63;
                    int cc = (dd >> 3) ^ (row & 7);
                    Kb[(size_t)(b * 16 + h) * 131072 + kt * 4096 + row * 64 +
                       cc * 8 + (dd & 7)] = (bf16_t)acc[mt][nt][rr];
                }
            }
        }
    } else {
#pragma unroll
        for (int mt = 0; mt < 4; mt++) {
            int sg = m0 + wm * 64 + mt * 16 + l16;
            int b = sg >> 11, sl = sg & 2047;
            int kt = sl >> 6, srow = sl & 63;
#pragma unroll
            for (int nt = 0; nt < 4; nt++) {
                int dg_base = n0 + wn * 64 + nt * 16 + quad * 4;
#pragma unroll
                for (int rr = 0; rr < 4; rr++) {
                    int dg = dg_base + rr;
                    int h = dg >> 6, dd = dg & 63;
                    int cc = (srow >> 3) ^ (dd & 7);
                    Vb[(size_t)(b * 16 + h) * 131072 + kt * 4096 + dd * 64 +
                       cc * 8 + (srow & 7)] = (bf16_t)acc[mt][nt][rr];
                }
            }
        }
    }
}

// ---------------- attention: no-LDS K/V, no barriers ----------------
// grid 512. f&7 = XCD slot; per XCD: 4 bh x 16 qtj (128-row tiles).
// Co-resident f, f+256 -> qtj q and 15-q (balanced, 34 iters const).
__global__ __launch_bounds__(256) void attn_k(
    const bf16_t* __restrict__ Qb, const bf16_t* __restrict__ Kb,
    const bf16_t* __restrict__ Vb, bf16_t* __restrict__ ctxb) {
    const int S = 2048;
    __shared__ __align__(16) bf16_t Ps[2][4096];
    int tid = threadIdx.x, wave = tid >> 6, lane = tid & 63;
    int quad = lane >> 4, l16 = lane & 15;

    int f = blockIdx.x;
    int xcd = f & 7;
    int j = f >> 3;              // 0..63
    int hi = j >> 5;
    int idx = j & 31;
    int qtj = hi ? (15 - (idx & 15)) : (idx & 15);
    int bh = xcd * 4 + ((idx >> 4) + 2 * hi);
    int h = bh & 15, b = bh >> 4;
    int q0 = qtj * 128;

    const bf16_t* Qbh = Qb + (size_t)bh * S * 64;
    const bf16_t* Kbh = Kb + (size_t)bh * 131072;
    const bf16_t* Vbh = Vb + (size_t)bh * 131072;

    const float qs = 0.125f * 1.44269504f;
    bf16x8 aQ[2][2];
#pragma unroll
    for (int sub = 0; sub < 2; sub++) {
        const bf16_t* rq = Qbh + (size_t)(q0 + sub * 64 + wave * 16 + l16) * 64;
#pragma unroll
        for (int ks = 0; ks < 2; ks++) {
            bf16x8 t = *(const bf16x8*)(rq + ks * 32 + quad * 8);
#pragma unroll
            for (int jj = 0; jj < 8; jj++) t[jj] = (bf16_t)((float)t[jj] * qs);
            aQ[sub][ks] = t;
        }
    }

    float L[2] = {0.f, 0.f};
    f32x4 O[2][4];
#pragma unroll
    for (int sub = 0; sub < 2; sub++)
#pragma unroll
        for (int i = 0; i < 4; i++) O[sub][i] = (f32x4){0.f, 0.f, 0.f, 0.f};

    // per-lane fragment offsets within a 64x64 tile (match qkv's swizzle)
    int koff[4][2];
#pragma unroll
    for (int nt = 0; nt < 4; nt++)
#pragma unroll
        for (int ks = 0; ks < 2; ks++)
            koff[nt][ks] = (nt * 16 + l16) * 64 + ((ks * 4 + quad) ^ (l16 & 7)) * 8;

    int tmax = 2 * qtj + 2;
#pragma unroll 1
    for (int kt = 0; kt < tmax; kt++) {
        const bf16_t* kbase = Kbh + kt * 4096;
        const bf16_t* vbase = Vbh + kt * 4096;
        bf16x8 kf[4][2], vf[4][2];
#pragma unroll
        for (int nt = 0; nt < 4; nt++)
#pragma unroll
            for (int ks = 0; ks < 2; ks++) {
                kf[nt][ks] = *(const bf16x8*)(kbase + koff[nt][ks]);
                vf[nt][ks] = *(const bf16x8*)(vbase + koff[nt][ks]);
            }

        bool do_lo = (kt < tmax - 1);
        if (do_lo) {
            f32x4 sc[4];
#pragma unroll
            for (int nt = 0; nt < 4; nt++) {
                f32x4 ss = (f32x4){0.f, 0.f, 0.f, 0.f};
                ss = __builtin_amdgcn_mfma_f32_16x16x32_bf16(kf[nt][0], aQ[0][0], ss, 0, 0, 0);
                ss = __builtin_amdgcn_mfma_f32_16x16x32_bf16(kf[nt][1], aQ[0][1], ss, 0, 0, 0);
                sc[nt] = ss;
            }
            if (kt == tmax - 2) {
                int qg = q0 + wave * 16 + l16;
#pragma unroll
                for (int nt = 0; nt < 4; nt++)
#pragma unroll
                    for (int rr = 0; rr < 4; rr++)
                        if (kt * 64 + nt * 16 + quad * 4 + rr > qg) sc[nt][rr] = -1e30f;
            }
            L[0] += exp_pwrite(sc, Ps[0], wave, quad, l16);
        }
        {
            f32x4 sc[4];
#pragma unroll
            for (int nt = 0; nt < 4; nt++) {
                f32x4 ss = (f32x4){0.f, 0.f, 0.f, 0.f};
                ss = __builtin_amdgcn_mfma_f32_16x16x32_bf16(kf[nt][0], aQ[1][0], ss, 0, 0, 0);
                ss = __builtin_amdgcn_mfma_f32_16x16x32_bf16(kf[nt][1], aQ[1][1], ss, 0, 0, 0);
                sc[nt] = ss;
            }
            if (kt == tmax - 1) {
                int qg = q0 + 64 + wave * 16 + l16;
#pragma unroll
                for (int nt = 0; nt < 4; nt++)
#pragma unroll
                    for (int rr = 0; rr < 4; rr++)
                        if (kt * 64 + nt * 16 + quad * 4 + rr > qg) sc[nt][rr] = -1e30f;
            }
            L[1] += exp_pwrite(sc, Ps[1], wave, quad, l16);
        }

        // O += P @ V (Ps slab is wave-private; wave-local LDS is in-order)
#pragma unroll
        for (int ks = 0; ks < 2; ks++) {
            int csw = ((ks * 4 + quad) ^ (l16 & 7)) * 8;
            bf16x8 aPhi = *(const bf16x8*)(Ps[1] + (wave * 16 + l16) * 64 + csw);
            bf16x8 aPlo;
            if (do_lo) aPlo = *(const bf16x8*)(Ps[0] + (wave * 16 + l16) * 64 + csw);
#pragma unroll
            for (int nt = 0; nt < 4; nt++) {
                O[1][nt] = __builtin_amdgcn_mfma_f32_16x16x32_bf16(aPhi, vf[nt][ks],
                                                                   O[1][nt], 0, 0, 0);
                if (do_lo)
                    O[0][nt] = __builtin_amdgcn_mfma_f32_16x16x32_bf16(aPlo, vf[nt][ks],
                                                                       O[0][nt], 0, 0, 0);
            }
        }
    }

#pragma unroll
    for (int sub = 0; sub < 2; sub++) {
        float il[4];
#pragma unroll
        for (int rr = 0; rr < 4; rr++) il[rr] = 1.f / __shfl(L[sub], quad * 4 + rr);
#pragma unroll
        for (int nt = 0; nt < 4; nt++) {
#pragma unroll
            for (int rr = 0; rr < 4; rr++) {
                int qoff = q0 + sub * 64 + wave * 16 + quad * 4 + rr;
                int col = h * 64 + nt * 16 + l16;
                ctxb[(size_t)(b * 2048 + qoff) * 1024 + col] =
                    (bf16_t)(O[sub][nt][rr] * il[rr]);
            }
        }
    }
}

// ---------------- out projection (r6 body, unchanged) ----------------
__global__ __launch_bounds__(256) void out_k(
    const bf16_t* __restrict__ ctxb, const bf16_t* __restrict__ WoT,
    const float* __restrict__ bo, float* __restrict__ out) {
    const int KD = 1024;
    __shared__ __align__(16) bf16_t As[2][2048];
    __shared__ __align__(16) bf16_t Bs[2][4096];
    int tid = threadIdx.x;
    int wave = tid >> 6, lane = tid & 63;
    int quad = lane >> 4, l16 = lane & 15;
    int wm = wave >> 1, wn = wave & 1;
    int m0 = blockIdx.x * 64;
    int n0 = blockIdx.y * 128;

    int r = tid >> 2;
    int c8 = (((tid & 3) ^ ((tid >> 3) & 3))) * 8;
    const bf16_t* gA  = ctxb + (size_t)(m0 + r) * KD + c8;
    const bf16_t* gB0 = WoT + (size_t)(n0 + r) * KD + c8;
    const bf16_t* gB1 = WoT + (size_t)(n0 + 64 + r) * KD + c8;

    f32x4 acc[2][4];
#pragma unroll
    for (int i = 0; i < 2; i++)
#pragma unroll
        for (int j = 0; j < 4; j++) acc[i][j] = (f32x4){0.f, 0.f, 0.f, 0.f};

    int4 sa = *(const int4*)gA;
    int4 sb0 = *(const int4*)gB0, sb1 = *(const int4*)gB1;
    *(int4*)(As[0] + tid * 8) = sa;
    *(int4*)(Bs[0] + tid * 8) = sb0;
    *(int4*)(Bs[0] + 2048 + tid * 8) = sb1;
    sa = *(const int4*)(gA + 32);
    sb0 = *(const int4*)(gB0 + 32); sb1 = *(const int4*)(gB1 + 32);

    int csw = (quad ^ ((l16 >> 1) & 3)) * 8;
#pragma unroll 1
    for (int kk = 0; kk < 32; kk += 2) {
        barrier_lgkm();
        bf16x8 af[2], bfr[4];
#pragma unroll
        for (int mt = 0; mt < 2; mt++)
            af[mt] = *(const bf16x8*)(As[0] + (wm * 32 + mt * 16 + l16) * 32 + csw);
#pragma unroll
        for (int nt = 0; nt < 4; nt++)
            bfr[nt] = *(const bf16x8*)(Bs[0] + (wn * 64 + nt * 16 + l16) * 32 + csw);
        *(int4*)(As[1] + tid * 8) = sa;
        *(int4*)(Bs[1] + tid * 8) = sb0;
        *(int4*)(Bs[1] + 2048 + tid * 8) = sb1;
        if (kk + 2 < 32) {
            int k0 = (kk + 2) * 32;
            sa = *(const int4*)(gA + k0);
            sb0 = *(const int4*)(gB0 + k0); sb1 = *(const int4*)(gB1 + k0);
        }
#pragma unroll
        for (int mt = 0; mt < 2; mt++)
#pragma unroll
            for (int nt = 0; nt < 4; nt++)
                acc[mt][nt] = __builtin_amdgcn_mfma_f32_16x16x32_bf16(
                    af[mt], bfr[nt], acc[mt][nt], 0, 0, 0);
        barrier_lgkm();
#pragma unroll
        for (int mt = 0; mt < 2; mt++)
            af[mt] = *(const bf16x8*)(As[1] + (wm * 32 + mt * 16 + l16) * 32 + csw);
#pragma unroll
        for (int nt = 0; nt < 4; nt++)
            bfr[nt] = *(const bf16x8*)(Bs[1] + (wn * 64 + nt * 16 + l16) * 32 + csw);
        if (kk + 2 < 32) {
            *(int4*)(As[0] + tid * 8) = sa;
            *(int4*)(Bs[0] + tid * 8) = sb0;
            *(int4*)(Bs[0] + 2048 + tid * 8) = sb1;
            if (kk + 3 < 32) {
                int k0 = (kk + 3) * 32;
                sa = *(const int4*)(gA + k0);
                sb0 = *(const int4*)(gB0 + k0); sb1 = *(const int4*)(gB1 + k0);
            }
        }
#pragma unroll
        for (int mt = 0; mt < 2; mt++)
#pragma unroll
            for (int nt = 0; nt < 4; nt++)
                acc[mt][nt] = __builtin_amdgcn_mfma_f32_16x16x32_bf16(
                    af[mt], bfr[nt], acc[mt][nt], 0, 0, 0);
    }

#pragma unroll
    for (int mt = 0; mt < 2; mt++) {
        int mg_base = m0 + wm * 32 + mt * 16 + quad * 4;
#pragma unroll
        for (int nt = 0; nt < 4; nt++) {
            int ng = n0 + wn * 64 + nt * 16 + l16;
            float bv = bo[ng];
#pragma unroll
            for (int rr = 0; rr < 4; rr++) {
                int mg = mg_base + rr;
                out[(size_t)mg * 1024 + ng] = acc[mt][nt][rr] + bv;
            }
        }
    }
}

extern "C" void kernel_launch(void* const* d_in, const int* in_sizes, int n_in,
                              void* d_out, int out_size, void* d_ws, size_t ws_size,
                              hipStream_t stream) {
    const float* x  = (const float*)d_in[0];
    const float* Wq = (const float*)d_in[1];
    const float* Wk = (const float*)d_in[2];
    const float* Wv = (const float*)d_in[3];
    const float* Wo = (const float*)d_in[4];
    const float* bo = (const float*)d_in[5];
    float* out = (float*)d_out;
    char* ws = (char*)d_ws;

    bf16_t* xb   = (bf16_t*)ws;                  // 8 MB
    bf16_t* WTs  = (bf16_t*)(ws + (8u << 20));   // 4x2 MB
    bf16_t* Qb   = (bf16_t*)(ws + (16u << 20));  // 8 MB natural
    bf16_t* Kb   = (bf16_t*)(ws + (24u << 20));  // 8 MB tiled-swizzled
    bf16_t* Vb   = (bf16_t*)(ws + (32u << 20));  // 8 MB tiled-swizzled V^T
    bf16_t* ctxb = (bf16_t*)(ws + (40u << 20));  // 8 MB

    prep_k<<<5120, 256, 0, stream>>>(x, Wq, Wk, Wv, Wo, xb, WTs);
    qkv_k<<<dim3(32, 8, 3), 256, 0, stream>>>(xb, WTs, Qb, Kb, Vb);
    attn_k<<<512, 256, 0, stream>>>(Qb, Kb, Vb, ctxb);
    out_k<<<dim3(64, 8), 256, 0, stream>>>(ctxb, WTs + 3145728, bo, out);
}